// Round 8
// baseline (642.986 us; speedup 1.0000x reference)
//
#include <hip/hip_runtime.h>
#include <hip/hip_bf16.h>
#include <stdint.h>

#define NN 50000
#define NE 800000
#define IND 128
#define HID 256
#define MPAD 50048      // 782 * 64
#define NBLK 49         // ceil(NN/1024)

typedef unsigned int uint32;
typedef unsigned short ushort_t;
typedef __attribute__((ext_vector_type(8))) short short8;
typedef __attribute__((ext_vector_type(4))) float f32x4;

typedef const __attribute__((address_space(1))) void* gptr_t;
typedef __attribute__((address_space(3))) void* lptr_t;

__device__ __forceinline__ ushort_t f2b(float f) {
  uint32 u = __float_as_uint(f);
  u = (u + 0x7fffu + ((u >> 16) & 1u)) >> 16;
  return (ushort_t)u;
}
__device__ __forceinline__ float blo(uint32 u) { return __uint_as_float(u << 16); }
__device__ __forceinline__ float bhi(uint32 u) { return __uint_as_float(u & 0xffff0000u); }
__device__ __forceinline__ uint32 pack2(float a, float b) {
  return (uint32)f2b(a) | ((uint32)f2b(b) << 16);
}

// ---------------- CSR build ----------------
__global__ void hist_k(const int* __restrict__ dst, int* __restrict__ cnt) {
  int e = blockIdx.x * 256 + threadIdx.x;
  if (e < NE) atomicAdd(&cnt[dst[e]], 1);
}

__global__ void bsum_k(const int* __restrict__ cnt, int* __restrict__ bsum) {
  __shared__ int ws[16];
  const int tid = threadIdx.x, ln = tid & 63, wv = tid >> 6;
  int i = blockIdx.x * 1024 + tid;
  int v = (i < NN) ? cnt[i] : 0;
#pragma unroll
  for (int d = 32; d; d >>= 1) v += __shfl_down(v, d, 64);
  if (ln == 0) ws[wv] = v;
  __syncthreads();
  if (tid < 16) {
    int s = ws[tid];
#pragma unroll
    for (int d = 8; d; d >>= 1) s += __shfl_down(s, d, 64);
    if (tid == 0) bsum[blockIdx.x] = s;
  }
}

__global__ void bscan_k(int* __restrict__ bsum, int* __restrict__ rp) {
  int tid = threadIdx.x;
  int v = (tid < NBLK) ? bsum[tid] : 0;
  int x = v;
#pragma unroll
  for (int d = 1; d < 64; d <<= 1) {
    int t = __shfl_up(x, d, 64);
    if (tid >= d) x += t;
  }
  if (tid < NBLK) bsum[tid] = x - v;
  if (tid == 0) rp[NN] = NE;
}

__global__ void scan2_k(const int* __restrict__ cnt, const int* __restrict__ bsum,
                        int* __restrict__ rp, int* __restrict__ cur) {
  __shared__ int ws[16];
  const int tid = threadIdx.x, ln = tid & 63, wv = tid >> 6;
  int i = blockIdx.x * 1024 + tid;
  int v = (i < NN) ? cnt[i] : 0;
  int x = v;
#pragma unroll
  for (int d = 1; d < 64; d <<= 1) {
    int t = __shfl_up(x, d, 64);
    if (ln >= d) x += t;
  }
  if (ln == 63) ws[wv] = x;
  __syncthreads();
  if (tid < 16) {
    int s = ws[tid];
#pragma unroll
    for (int d = 1; d < 16; d <<= 1) {
      int t = __shfl_up(s, d, 64);
      if (tid >= d) s += t;
    }
    ws[tid] = s;
  }
  __syncthreads();
  int excl = x - v + (wv ? ws[wv - 1] : 0) + bsum[blockIdx.x];
  if (i < NN) { rp[i] = excl; cur[i] = excl; }
}

__global__ void scatter_k(const int* __restrict__ src, const int* __restrict__ dst,
                          int* __restrict__ cur, int* __restrict__ esrc) {
  int e = blockIdx.x * 256 + threadIdx.x;
  if (e < NE) {
    int p = atomicAdd(&cur[dst[e]], 1);
    esrc[p] = src[e];
  }
}

// ---------------- setup: weight transposes + BN fold + zero(cur) + x->bf16 ----------------
__global__ void prep_k(const float* __restrict__ w1_0, const float* __restrict__ w2_0,
                       const float* __restrict__ w1_r, const float* __restrict__ w2_r,
                       const float* b1_0, const float* b2_0, const float* g0,
                       const float* be0, const float* m0, const float* v0,
                       const float* b1_r, const float* b2_r, const float* g_r,
                       const float* be_r, const float* m_r, const float* v_r,
                       const float* __restrict__ x,
                       ushort_t* __restrict__ wt,
                       float* bi1, float* sc2, float* bi2,
                       int* __restrict__ cur, ushort_t* __restrict__ xb) {
  const int which = blockIdx.y;
  const int tid = threadIdx.x;
  if (which < 6) {
    const int n = blockIdx.x, k = tid;
    const float* w; ushort_t* o; int K = HID;
    switch (which) {
      case 0: w = w1_0; o = wt; K = IND; break;
      case 1: w = w2_0; o = wt + HID * IND; break;
      case 2: w = w1_r; o = wt + HID * IND + 1 * HID * HID; break;
      case 3: w = w2_r; o = wt + HID * IND + 2 * HID * HID; break;
      case 4: w = w1_r + HID * HID; o = wt + HID * IND + 3 * HID * HID; break;
      default: w = w2_r + HID * HID; o = wt + HID * IND + 4 * HID * HID; break;
    }
    if (k < K) o[n * K + k] = f2b(w[(size_t)k * HID + n]);
  } else if (which == 6) {
    const int l = blockIdx.x;
    if (l >= 3) return;
    const int j = tid;
    float b1, b2, g, be, m, v;
    if (l == 0) { b1 = b1_0[j]; b2 = b2_0[j]; g = g0[j]; be = be0[j]; m = m0[j]; v = v0[j]; }
    else { int o = (l - 1) * HID + j; b1 = b1_r[o]; b2 = b2_r[o]; g = g_r[o]; be = be_r[o]; m = m_r[o]; v = v_r[o]; }
    int o = l * HID + j;
    bi1[o] = b1;
    float s = g * rsqrtf(v + 1e-5f);
    sc2[o] = s;
    bi2[o] = (b2 - m) * s + be;
  } else if (which == 7) {
    int i = blockIdx.x * 256 + tid;    // 65536 >= NN
    if (i < NN) cur[i] = 0;
  } else {
    const int n = NN * IND / 2;
    for (int i = blockIdx.x * 256 + tid; i < n; i += 256 * 256) {
      float2 f = ((const float2*)x)[i];
      ((uint32*)xb)[i] = pack2(f.x, f.y);
    }
  }
}

// ---------------- fused GIN layer: out = BN(lrelu((h+agg) W1 + b1) W2 + b2) ----------------
// 64-node block (grid 782), 4 waves.
// Phase 0: gather-aggregate 64 rows (self + neighbors) -> LDS As (bf16, stride 264).
// Phase 1: C1 = lrelu(As*W1 + b1) -> same LDS buffer (As dead after k-loop).
// Phase 2: C2 = C1*W2 with folded BN (+opt lrelu) -> global.
__global__ __launch_bounds__(256, 3) void fused_k(
    const ushort_t* __restrict__ hin, const int* __restrict__ rp,
    const int* __restrict__ esrc, const ushort_t* __restrict__ B1t,
    const ushort_t* __restrict__ B2t, const float* __restrict__ bi1,
    const float* __restrict__ sc2, const float* __restrict__ bi2,
    void* __restrict__ out, int K1, int lrelu2, int f32out) {
  __shared__ ushort_t AC1[64 * 264];   // 33 KB: As in phases 0-1, C1 in phase 2
  __shared__ ushort_t Bs[256 * 32];    // 16 KB
  const int tid = threadIdx.x;
  const int lane = tid & 63;
  const int wid = tid >> 6;
  const int m0 = blockIdx.x * 64;
  const int srow = tid >> 2;           // 0..63
  const int sch = (tid & 3) * 8;
  const int fr = lane & 15;
  const int fk = (lane >> 4) * 8;
  const int er = lane >> 4;
  const int ec = lane & 15;

  // ---- phase 0: aggregate. wave handles nodes m0 + t*4 + wid, t=0..15 ----
  if (K1 == 256) {
    const uint2* hp = (const uint2*)hin;
    for (int t = 0; t < 16; t++) {
      int node = m0 + t * 4 + wid;
      int row = t * 4 + wid;
      float a0 = 0.f, a1 = 0.f, a2 = 0.f, a3 = 0.f;
      if (node < NN) {
        uint2 v = hp[(size_t)node * 64 + lane];
        a0 = blo(v.x); a1 = bhi(v.x); a2 = blo(v.y); a3 = bhi(v.y);
        int e0 = rp[node], e1 = rp[node + 1];
        int e = e0;
        for (; e + 8 <= e1; e += 8) {
          int s[8];
#pragma unroll
          for (int q = 0; q < 8; q++) s[q] = esrc[e + q];
          uint2 u[8];
#pragma unroll
          for (int q = 0; q < 8; q++) u[q] = hp[(size_t)s[q] * 64 + lane];
#pragma unroll
          for (int q = 0; q < 8; q++) {
            a0 += blo(u[q].x); a1 += bhi(u[q].x); a2 += blo(u[q].y); a3 += bhi(u[q].y);
          }
        }
        for (; e < e1; e++) {
          int s = esrc[e];
          uint2 u = hp[(size_t)s * 64 + lane];
          a0 += blo(u.x); a1 += bhi(u.x); a2 += blo(u.y); a3 += bhi(u.y);
        }
      }
      uint2 o; o.x = pack2(a0, a1); o.y = pack2(a2, a3);
      *(uint2*)((char*)AC1 + (size_t)row * 528 + lane * 8) = o;
    }
  } else {  // K1 == 128
    const uint32* hp = (const uint32*)hin;
    for (int t = 0; t < 16; t++) {
      int node = m0 + t * 4 + wid;
      int row = t * 4 + wid;
      float a0 = 0.f, a1 = 0.f;
      if (node < NN) {
        uint32 v = hp[(size_t)node * 64 + lane];
        a0 = blo(v); a1 = bhi(v);
        int e0 = rp[node], e1 = rp[node + 1];
        int e = e0;
        for (; e + 8 <= e1; e += 8) {
          int s[8];
#pragma unroll
          for (int q = 0; q < 8; q++) s[q] = esrc[e + q];
          uint32 u[8];
#pragma unroll
          for (int q = 0; q < 8; q++) u[q] = hp[(size_t)s[q] * 64 + lane];
#pragma unroll
          for (int q = 0; q < 8; q++) { a0 += blo(u[q]); a1 += bhi(u[q]); }
        }
        for (; e < e1; e++) {
          int s = esrc[e];
          uint32 u = hp[(size_t)s * 64 + lane];
          a0 += blo(u); a1 += bhi(u);
        }
      }
      *(uint32*)((char*)AC1 + (size_t)row * 528 + lane * 4) = pack2(a0, a1);
    }
  }
  __syncthreads();

  // ---- phase 1: As (64 x K1, LDS) * W1 (K1 x 256) ----
  f32x4 zero = {0.f, 0.f, 0.f, 0.f};
  f32x4 acc[4][4];
#pragma unroll
  for (int i = 0; i < 4; i++)
#pragma unroll
    for (int j = 0; j < 4; j++) acc[i][j] = zero;

  for (int kk = 0; kk < K1; kk += 32) {
#pragma unroll
    for (int p = 0; p < 4; p++)
      __builtin_amdgcn_global_load_lds(
          (gptr_t)(B1t + (size_t)(p * 64 + srow) * K1 + kk + sch),
          (lptr_t)(Bs + (p * 64 + srow) * 32 + sch), 16, 0, 0);
    __syncthreads();
    short8 af[4], bfv[4];
#pragma unroll
    for (int i = 0; i < 4; i++)
      af[i] = *(const short8*)(AC1 + (i * 16 + fr) * 264 + kk + fk);
#pragma unroll
    for (int j = 0; j < 4; j++)
      bfv[j] = *(const short8*)(Bs + (wid * 64 + j * 16 + fr) * 32 + fk);
#pragma unroll
    for (int i = 0; i < 4; i++)
#pragma unroll
      for (int j = 0; j < 4; j++)
        acc[i][j] = __builtin_amdgcn_mfma_f32_16x16x32_bf16(af[i], bfv[j], acc[i][j], 0, 0, 0);
    __syncthreads();
  }

  // C1 = lrelu(acc + b1) -> AC1 (As is dead: last k-iter's reads completed at the
  // loop-final __syncthreads)
#pragma unroll
  for (int j = 0; j < 4; j++) {
    int col = wid * 64 + j * 16 + ec;
    float b = bi1[col];
#pragma unroll
    for (int i = 0; i < 4; i++) {
#pragma unroll
      for (int r = 0; r < 4; r++) {
        int row = i * 16 + er * 4 + r;
        float v = acc[i][j][r] + b;
        v = (v > 0.f) ? v : 0.01f * v;
        AC1[row * 264 + col] = f2b(v);
      }
    }
  }
  __syncthreads();

  // ---- phase 2: C1 (64 x 256) * W2 (256 x 256) ----
  f32x4 acc2[4][4];
#pragma unroll
  for (int i = 0; i < 4; i++)
#pragma unroll
    for (int j = 0; j < 4; j++) acc2[i][j] = zero;

  for (int kk = 0; kk < HID; kk += 32) {
#pragma unroll
    for (int p = 0; p < 4; p++)
      __builtin_amdgcn_global_load_lds(
          (gptr_t)(B2t + (size_t)(p * 64 + srow) * HID + kk + sch),
          (lptr_t)(Bs + (p * 64 + srow) * 32 + sch), 16, 0, 0);
    __syncthreads();
    short8 af[4], bfv[4];
#pragma unroll
    for (int i = 0; i < 4; i++)
      af[i] = *(const short8*)(AC1 + (i * 16 + fr) * 264 + kk + fk);
#pragma unroll
    for (int j = 0; j < 4; j++)
      bfv[j] = *(const short8*)(Bs + (wid * 64 + j * 16 + fr) * 32 + fk);
#pragma unroll
    for (int i = 0; i < 4; i++)
#pragma unroll
      for (int j = 0; j < 4; j++)
        acc2[i][j] = __builtin_amdgcn_mfma_f32_16x16x32_bf16(af[i], bfv[j], acc2[i][j], 0, 0, 0);
    __syncthreads();
  }

  // epilogue: BN fold (+opt lrelu), store
#pragma unroll
  for (int j = 0; j < 4; j++) {
    int col = wid * 64 + j * 16 + ec;
    float s = sc2[col], b = bi2[col];
#pragma unroll
    for (int i = 0; i < 4; i++) {
#pragma unroll
      for (int r = 0; r < 4; r++) {
        int row = m0 + i * 16 + er * 4 + r;
        float v = acc2[i][j][r] * s + b;
        if (lrelu2) v = (v > 0.f) ? v : 0.01f * v;
        if (f32out) {
          if (row < NN) ((float*)out)[(size_t)row * HID + col] = v;
        } else {
          ((ushort_t*)out)[(size_t)row * HID + col] = f2b(v);
        }
      }
    }
  }
}

extern "C" void kernel_launch(void* const* d_in, const int* in_sizes, int n_in,
                              void* d_out, int out_size, void* d_ws, size_t ws_size,
                              hipStream_t stream) {
  const float* x    = (const float*)d_in[0];
  const int*   src  = (const int*)d_in[1];
  const int*   dst  = (const int*)d_in[2];
  const float* w1_0 = (const float*)d_in[3];
  const float* b1_0 = (const float*)d_in[4];
  const float* w2_0 = (const float*)d_in[5];
  const float* b2_0 = (const float*)d_in[6];
  const float* g0   = (const float*)d_in[7];
  const float* be0  = (const float*)d_in[8];
  const float* m0   = (const float*)d_in[9];
  const float* v0   = (const float*)d_in[10];
  const float* w1_r = (const float*)d_in[11];
  const float* b1_r = (const float*)d_in[12];
  const float* w2_r = (const float*)d_in[13];
  const float* b2_r = (const float*)d_in[14];
  const float* g_r  = (const float*)d_in[15];
  const float* be_r = (const float*)d_in[16];
  const float* m_r  = (const float*)d_in[17];
  const float* v_r  = (const float*)d_in[18];

  char* ws = (char*)d_ws;
  size_t off = 0;
  auto alloc = [&](size_t bytes) {
    void* p = ws + off;
    off = (off + bytes + 255) & ~(size_t)255;
    return p;
  };
  ushort_t* bufA  = (ushort_t*)alloc((size_t)MPAD * HID * 2);
  ushort_t* bufB  = (ushort_t*)alloc((size_t)MPAD * HID * 2);
  ushort_t* xb    = (ushort_t*)alloc((size_t)NN * IND * 2);
  int*      rp    = (int*)alloc((NN + 1) * sizeof(int));
  int*      cur   = (int*)alloc(NN * sizeof(int));
  int*      bsum  = (int*)alloc(NBLK * sizeof(int));
  int*      esrc  = (int*)alloc((size_t)NE * sizeof(int));
  ushort_t* wt    = (ushort_t*)alloc(((size_t)HID * IND + 5 * (size_t)HID * HID) * 2);
  float*    bi1   = (float*)alloc(3 * HID * sizeof(float));
  float*    sc2   = (float*)alloc(3 * HID * sizeof(float));
  float*    bi2   = (float*)alloc(3 * HID * sizeof(float));
  (void)ws_size; (void)in_sizes; (void)n_in; (void)out_size;

  ushort_t* w1_0t = wt;
  ushort_t* w2_0t = wt + HID * IND;
  ushort_t* w1r0t = wt + HID * IND + 1 * HID * HID;
  ushort_t* w2r0t = wt + HID * IND + 2 * HID * HID;
  ushort_t* w1r1t = wt + HID * IND + 3 * HID * HID;
  ushort_t* w2r1t = wt + HID * IND + 4 * HID * HID;

  // setup: weights, BN, zero(cur), x->bf16 (one launch)
  prep_k<<<dim3(256, 9), 256, 0, stream>>>(w1_0, w2_0, w1_r, w2_r,
                                           b1_0, b2_0, g0, be0, m0, v0,
                                           b1_r, b2_r, g_r, be_r, m_r, v_r,
                                           x, wt, bi1, sc2, bi2, cur, xb);
  // CSR build
  hist_k<<<(NE + 255) / 256, 256, 0, stream>>>(dst, cur);
  bsum_k<<<NBLK, 1024, 0, stream>>>(cur, bsum);
  bscan_k<<<1, 64, 0, stream>>>(bsum, rp);
  scan2_k<<<NBLK, 1024, 0, stream>>>(cur, bsum, rp, cur);
  scatter_k<<<(NE + 255) / 256, 256, 0, stream>>>(src, dst, cur, esrc);

  const int GG = MPAD / 64;  // 782
  fused_k<<<GG, 256, 0, stream>>>(xb,   rp, esrc, w1_0t, w2_0t, bi1,           sc2,           bi2,           bufA,  IND, 1, 0);
  fused_k<<<GG, 256, 0, stream>>>(bufA, rp, esrc, w1r0t, w2r0t, bi1 + HID,     sc2 + HID,     bi2 + HID,     bufB,  HID, 1, 0);
  fused_k<<<GG, 256, 0, stream>>>(bufB, rp, esrc, w1r1t, w2r1t, bi1 + 2 * HID, sc2 + 2 * HID, bi2 + 2 * HID, d_out, HID, 0, 1);
}